// Round 6
// baseline (3938.967 us; speedup 1.0000x reference)
//
#include <hip/hip_runtime.h>
#include <hip/hip_bf16.h>
#include <stdint.h>
#include <math.h>

#define T_TOKENS 16384
#define DIM      512
#define NEXP     8
#define TOK_TILE 16
#define BPE      2048     // blocks per expert = ceil(2*T / TOK_TILE)
#define HID      2048

// ---- JAX threefry2x32, key = (0, 42) ----
__device__ __forceinline__ void threefry2x32(uint32_t k0, uint32_t k1,
                                             uint32_t x0, uint32_t x1,
                                             uint32_t* o0, uint32_t* o1) {
  uint32_t ks0 = k0, ks1 = k1, ks2 = k0 ^ k1 ^ 0x1BD11BDAu;
#define TF_ROT(v, d) (((v) << (d)) | ((v) >> (32 - (d))))
#define TF_ROUND(r) { x0 += x1; x1 = TF_ROT(x1, r); x1 ^= x0; }
  x0 += ks0; x1 += ks1;
  TF_ROUND(13) TF_ROUND(15) TF_ROUND(26) TF_ROUND(6)
  x0 += ks1; x1 += ks2 + 1u;
  TF_ROUND(17) TF_ROUND(29) TF_ROUND(16) TF_ROUND(24)
  x0 += ks2; x1 += ks0 + 2u;
  TF_ROUND(13) TF_ROUND(15) TF_ROUND(26) TF_ROUND(6)
  x0 += ks0; x1 += ks1 + 3u;
  TF_ROUND(17) TF_ROUND(29) TF_ROUND(16) TF_ROUND(24)
  x0 += ks1; x1 += ks2 + 4u;
  TF_ROUND(13) TF_ROUND(15) TF_ROUND(26) TF_ROUND(6)
  x0 += ks2; x1 += ks0 + 5u;
#undef TF_ROUND
#undef TF_ROT
  *o0 = x0; *o1 = x1;
}

// ---- XLA ErfInv32 (Giles polynomial), unfused mul/add to match XLA CPU ----
__device__ __forceinline__ float erfinv_xla(float x) {
  float w = -log1pf(__fmul_rn(-x, x));
  float p;
  if (w < 5.0f) {
    w = __fadd_rn(w, -2.5f);
    p = 2.81022636e-08f;
    p = __fadd_rn(3.43273939e-07f, __fmul_rn(p, w));
    p = __fadd_rn(-3.5233877e-06f, __fmul_rn(p, w));
    p = __fadd_rn(-4.39150654e-06f, __fmul_rn(p, w));
    p = __fadd_rn(0.00021858087f, __fmul_rn(p, w));
    p = __fadd_rn(-0.00125372503f, __fmul_rn(p, w));
    p = __fadd_rn(-0.00417768164f, __fmul_rn(p, w));
    p = __fadd_rn(0.246640727f, __fmul_rn(p, w));
    p = __fadd_rn(1.50140941f, __fmul_rn(p, w));
  } else {
    w = __fadd_rn(sqrtf(w), -3.0f);
    p = -0.000200214257f;
    p = __fadd_rn(0.000100950558f, __fmul_rn(p, w));
    p = __fadd_rn(0.00134934322f, __fmul_rn(p, w));
    p = __fadd_rn(-0.00367342844f, __fmul_rn(p, w));
    p = __fadd_rn(0.00573950773f, __fmul_rn(p, w));
    p = __fadd_rn(-0.0076224613f, __fmul_rn(p, w));
    p = __fadd_rn(0.00943887047f, __fmul_rn(p, w));
    p = __fadd_rn(1.00167406f, __fmul_rn(p, w));
    p = __fadd_rn(2.83297682f, __fmul_rn(p, w));
  }
  return __fmul_rn(p, x);
}

// noise[i], i in [0, 131072): JAX normal(key(42), (16384,8)), partitionable
// threefry (default since jax 0.4.30): counter = iota(u64) -> (hi=0, lo=i),
// 32-bit combine = o0 ^ o1.
// Ladder if wrong: original concat scheme | counter (i,0).
__device__ __forceinline__ float jax_normal_at(uint32_t i) {
  uint32_t o0, o1;
  threefry2x32(0u, 42u, 0u, i, &o0, &o1);
  uint32_t bits = o0 ^ o1;
  float f = __fadd_rn(__uint_as_float((bits >> 9) | 0x3f800000u), -1.0f);
  const float lo = -0.99999994f;          // nextafter(-1, 0)
  float u = fmaxf(lo, __fadd_rn(__fmul_rn(f, 2.0f), lo));   // (hi-lo) folds to 2.0f
  return __fmul_rn(1.4142135623730951f, erfinv_xla(u));
}

// ---------------- Router: 1 wave per token, fp64 accumulation ----------------
__global__ __launch_bounds__(256) void router_kernel(
    const float* __restrict__ x, const float* __restrict__ Wr, const float* __restrict__ br,
    const float* __restrict__ Wn, const float* __restrict__ bn,
    int* __restrict__ counts, int* __restrict__ top_i, float* __restrict__ top_g) {
  int wave = threadIdx.x >> 6;
  int lane = threadIdx.x & 63;
  int t = blockIdx.x * 4 + wave;

  double accR[8], accN[8];
#pragma unroll
  for (int e = 0; e < 8; ++e) { accR[e] = 0.0; accN[e] = 0.0; }

  const float* xp = x + (size_t)t * DIM + lane * 8;
  float4 xa = *(const float4*)xp;
  float4 xb = *(const float4*)(xp + 4);
  float xv[8] = {xa.x, xa.y, xa.z, xa.w, xb.x, xb.y, xb.z, xb.w};

#pragma unroll
  for (int k = 0; k < 8; ++k) {
    int d = lane * 8 + k;
    float4 wra = *(const float4*)(Wr + (size_t)d * NEXP);
    float4 wrb = *(const float4*)(Wr + (size_t)d * NEXP + 4);
    float4 wna = *(const float4*)(Wn + (size_t)d * NEXP);
    float4 wnb = *(const float4*)(Wn + (size_t)d * NEXP + 4);
    float wr[8] = {wra.x, wra.y, wra.z, wra.w, wrb.x, wrb.y, wrb.z, wrb.w};
    float wn[8] = {wna.x, wna.y, wna.z, wna.w, wnb.x, wnb.y, wnb.z, wnb.w};
    double xk = (double)xv[k];
#pragma unroll
    for (int e = 0; e < 8; ++e) {
      accR[e] += xk * (double)wr[e];
      accN[e] += xk * (double)wn[e];
    }
  }
  // full-wave butterfly reduce in fp64
#pragma unroll
  for (int m = 1; m < 64; m <<= 1) {
#pragma unroll
    for (int e = 0; e < 8; ++e) {
      accR[e] += __shfl_xor(accR[e], m);
      accN[e] += __shfl_xor(accN[e], m);
    }
  }

  double noisy = -1.0e308;
  if (lane < 8) {
    int e = lane;
    double logit = accR[e] + (double)br[e];
    double nlin  = accN[e] + (double)bn[e];
    // noise bit-exact to JAX fp32 pipeline, then widened
    double noise = (double)jax_normal_at((uint32_t)t * 8u + (uint32_t)e);
    // softplus in fp64: stable log1p(exp(x))
    double sp = fmax(nlin, 0.0) + log1p(exp(-fabs(nlin)));
    noisy = logit + noise * sp;
  }
  double v[8];
#pragma unroll
  for (int e = 0; e < 8; ++e) v[e] = __shfl(noisy, e);

  if (lane == 0) {
    int i1 = 0; double v1 = v[0];
#pragma unroll
    for (int e = 1; e < 8; ++e) if (v[e] > v1) { v1 = v[e]; i1 = e; }
    int i2 = -1; double v2 = -1.0e308;
#pragma unroll
    for (int e = 0; e < 8; ++e) if (e != i1 && v[e] > v2) { v2 = v[e]; i2 = e; }
    double w2 = exp(v2 - v1);
    double s = 1.0 + w2;
    float g1 = (float)(1.0 / s), g2 = (float)(w2 / s);
    top_i[t * 2 + 0] = i1; top_g[t * 2 + 0] = g1;
    top_i[t * 2 + 1] = i2; top_g[t * 2 + 1] = g2;
    atomicAdd(&counts[i1], 1);
    atomicAdd(&counts[i2], 1);
  }
}

__global__ void scan_kernel(const int* __restrict__ counts, int* __restrict__ offsets) {
  if (threadIdx.x == 0 && blockIdx.x == 0) {
    int s = 0;
#pragma unroll
    for (int e = 0; e < NEXP; ++e) { offsets[e] = s; s += counts[e]; }
  }
}

__global__ __launch_bounds__(256) void scatter_kernel(
    const int* __restrict__ top_i, const float* __restrict__ top_g,
    const int* __restrict__ offsets, int* __restrict__ fill,
    int* __restrict__ ltok, float* __restrict__ lgate) {
  int i = blockIdx.x * 256 + threadIdx.x;   // slot index in [0, 2T)
  int e = top_i[i];
  float g = top_g[i];
  int pos = atomicAdd(&fill[e], 1);
  int dst = offsets[e] + pos;
  ltok[dst] = i >> 1;
  lgate[dst] = g;
}

// ---------------- Expert FFN: 16-token tile, fused 2-layer ----------------
// Accumulates gate-weighted output directly into fp32 d_out via atomicAdd.
__global__ __launch_bounds__(256) void expert_kernel(
    const float* __restrict__ x, const float* __restrict__ W1, const float* __restrict__ b1,
    const float* __restrict__ W2, const float* __restrict__ b2,
    const int* __restrict__ counts, const int* __restrict__ offsets,
    const int* __restrict__ ltok, const float* __restrict__ lgate,
    float* __restrict__ out) {
  int e = blockIdx.x / BPE;
  int blk = blockIdx.x % BPE;
  int cnt = counts[e];
  int start = blk * TOK_TILE;
  if (start >= cnt) return;
  int nrow = min(TOK_TILE, cnt - start);
  int base = offsets[e] + start;

  __shared__ float Xs[TOK_TILE][DIM];     // 32 KB
  __shared__ float Hs[TOK_TILE][132];     // 128-chunk + pad, 8.25 KB
  __shared__ int   toks[TOK_TILE];
  __shared__ float gates[TOK_TILE];

  int tid = threadIdx.x;
  if (tid < TOK_TILE) {
    int tk = 0; float g = 0.f;
    if (tid < nrow) { tk = ltok[base + tid]; g = lgate[base + tid]; }
    toks[tid] = tk; gates[tid] = g;
  }
  __syncthreads();

  // stage X tile (fp32 -> fp32 LDS)
#pragma unroll
  for (int it = 0; it < 4; ++it) {
    int gidx = it * 2048 + tid * 8;
    int r = gidx >> 9, c = gidx & 511;
    float4 va, vb;
    if (r < nrow) {
      const float* xp = x + (size_t)toks[r] * DIM + c;
      va = *(const float4*)xp;
      vb = *(const float4*)(xp + 4);
    } else {
      va = make_float4(0.f, 0.f, 0.f, 0.f);
      vb = va;
    }
    *(float4*)&Xs[r][c]     = va;
    *(float4*)&Xs[r][c + 4] = vb;
  }
  __syncthreads();

  int jl = tid & 63;        // layer-1: h-cols jl, jl+64 inside the 128-chunk
  int tq = tid >> 6;        // layer-1: tokens tq, tq+4, tq+8, tq+12
  int dc0 = tid, dc1 = tid + 256;   // layer-2: output cols

  float Y0[TOK_TILE], Y1[TOK_TILE];
#pragma unroll
  for (int t = 0; t < TOK_TILE; ++t) { Y0[t] = 0.f; Y1[t] = 0.f; }

  const float* w2e = W2 + (size_t)e * HID * DIM;

  for (int hc = 0; hc < HID / 128; ++hc) {
    // ---- layer 1: H[t][hc*128 + {jl, jl+64}] for 4 tokens ----
    const float* w1a = W1 + (size_t)e * DIM * HID + (size_t)hc * 128 + jl;
    const float* w1b = w1a + 64;
    float a00 = 0.f, a01 = 0.f, a10 = 0.f, a11 = 0.f;
    float a20 = 0.f, a21 = 0.f, a30 = 0.f, a31 = 0.f;
    for (int d = 0; d < DIM; d += 4) {
      float4 x0 = *(const float4*)&Xs[tq][d];
      float4 x1 = *(const float4*)&Xs[tq + 4][d];
      float4 x2 = *(const float4*)&Xs[tq + 8][d];
      float4 x3 = *(const float4*)&Xs[tq + 12][d];
      float wa0 = w1a[(size_t)(d + 0) * HID];
      float wa1 = w1a[(size_t)(d + 1) * HID];
      float wa2 = w1a[(size_t)(d + 2) * HID];
      float wa3 = w1a[(size_t)(d + 3) * HID];
      float wb0 = w1b[(size_t)(d + 0) * HID];
      float wb1 = w1b[(size_t)(d + 1) * HID];
      float wb2 = w1b[(size_t)(d + 2) * HID];
      float wb3 = w1b[(size_t)(d + 3) * HID];
      a00 += x0.x * wa0 + x0.y * wa1 + x0.z * wa2 + x0.w * wa3;
      a01 += x0.x * wb0 + x0.y * wb1 + x0.z * wb2 + x0.w * wb3;
      a10 += x1.x * wa0 + x1.y * wa1 + x1.z * wa2 + x1.w * wa3;
      a11 += x1.x * wb0 + x1.y * wb1 + x1.z * wb2 + x1.w * wb3;
      a20 += x2.x * wa0 + x2.y * wa1 + x2.z * wa2 + x2.w * wa3;
      a21 += x2.x * wb0 + x2.y * wb1 + x2.z * wb2 + x2.w * wb3;
      a30 += x3.x * wa0 + x3.y * wa1 + x3.z * wa2 + x3.w * wa3;
      a31 += x3.x * wb0 + x3.y * wb1 + x3.z * wb2 + x3.w * wb3;
    }
    float ba = b1[e * HID + hc * 128 + jl];
    float bb = b1[e * HID + hc * 128 + jl + 64];
    __syncthreads();   // previous layer-2 finished reading Hs
    Hs[tq][jl]           = fmaxf(a00 + ba, 0.f);
    Hs[tq][jl + 64]      = fmaxf(a01 + bb, 0.f);
    Hs[tq + 4][jl]       = fmaxf(a10 + ba, 0.f);
    Hs[tq + 4][jl + 64]  = fmaxf(a11 + bb, 0.f);
    Hs[tq + 8][jl]       = fmaxf(a20 + ba, 0.f);
    Hs[tq + 8][jl + 64]  = fmaxf(a21 + bb, 0.f);
    Hs[tq + 12][jl]      = fmaxf(a30 + ba, 0.f);
    Hs[tq + 12][jl + 64] = fmaxf(a31 + bb, 0.f);
    __syncthreads();

    // ---- layer 2: Y[t][dc0], Y[t][dc1] += H-chunk @ W2-chunk ----
    for (int jj = 0; jj < 128; jj += 4) {
      size_t row = (size_t)(hc * 128 + jj) * DIM;
      float wA0 = w2e[row + dc0];
      float wB0 = w2e[row + dc1];
      float wA1 = w2e[row + DIM + dc0];
      float wB1 = w2e[row + DIM + dc1];
      float wA2 = w2e[row + 2 * DIM + dc0];
      float wB2 = w2e[row + 2 * DIM + dc1];
      float wA3 = w2e[row + 3 * DIM + dc0];
      float wB3 = w2e[row + 3 * DIM + dc1];
#pragma unroll
      for (int t = 0; t < TOK_TILE; ++t) {
        float4 hv = *(const float4*)&Hs[t][jj];
        Y0[t] += hv.x * wA0 + hv.y * wA1 + hv.z * wA2 + hv.w * wA3;
        Y1[t] += hv.x * wB0 + hv.y * wB1 + hv.z * wB2 + hv.w * wB3;
      }
    }
  }

  float b2v0 = b2[e * DIM + dc0];
  float b2v1 = b2[e * DIM + dc1];
  for (int t = 0; t < nrow; ++t) {
    float g = gates[t];
    size_t ob = (size_t)toks[t] * DIM;
    atomicAdd(&out[ob + dc0], g * (Y0[t] + b2v0));
    atomicAdd(&out[ob + dc1], g * (Y1[t] + b2v1));
  }
}

extern "C" void kernel_launch(void* const* d_in, const int* in_sizes, int n_in,
                              void* d_out, int out_size, void* d_ws, size_t ws_size,
                              hipStream_t stream) {
  const float* x  = (const float*)d_in[0];
  const float* Wr = (const float*)d_in[1];
  const float* br = (const float*)d_in[2];
  const float* Wn = (const float*)d_in[3];
  const float* bn = (const float*)d_in[4];
  const float* W1 = (const float*)d_in[5];
  const float* b1 = (const float*)d_in[6];
  const float* W2 = (const float*)d_in[7];
  const float* b2 = (const float*)d_in[8];
  float* out = (float*)d_out;    // fp32 output, per reference dtype

  uint8_t* wsb = (uint8_t*)d_ws;
  int* counts  = (int*)(wsb);
  int* offsets = (int*)(wsb + 32);
  int* fill    = (int*)(wsb + 64);
  int* top_i   = (int*)(wsb + 128);
  float* top_g = (float*)(wsb + 128 + 131072);
  int* ltok    = (int*)(wsb + 128 + 262144);
  float* lgate = (float*)(wsb + 128 + 393216);

  // zero the output (timed replays poison it with 0xAA) and the small counters
  hipMemsetAsync(out, 0, (size_t)out_size * sizeof(float), stream);
  hipMemsetAsync(wsb, 0, 128, stream);

  router_kernel<<<T_TOKENS / 4, 256, 0, stream>>>(x, Wr, br, Wn, bn, counts, top_i, top_g);
  scan_kernel<<<1, 64, 0, stream>>>(counts, offsets);
  scatter_kernel<<<(2 * T_TOKENS) / 256, 256, 0, stream>>>(top_i, top_g, offsets, fill, ltok, lgate);
  expert_kernel<<<NEXP * BPE, 256, 0, stream>>>(x, W1, b1, W2, b2, counts, offsets, ltok, lgate, out);
}

// Round 7
// 1193.881 us; speedup vs baseline: 3.2993x; 3.2993x over previous
//
#include <hip/hip_runtime.h>
#include <hip/hip_bf16.h>
#include <stdint.h>
#include <math.h>

#define T_TOKENS 16384
#define DIM      512
#define NEXP     8
#define HID      2048

typedef __attribute__((ext_vector_type(8))) __bf16 bf16x8;
typedef __attribute__((ext_vector_type(4))) float  f32x4;

__device__ __forceinline__ f32x4 mfma16(bf16x8 a, bf16x8 b, f32x4 c) {
  return __builtin_amdgcn_mfma_f32_16x16x32_bf16(a, b, c, 0, 0, 0);
}

// ---- JAX threefry2x32, key = (0, 42) ----
__device__ __forceinline__ void threefry2x32(uint32_t k0, uint32_t k1,
                                             uint32_t x0, uint32_t x1,
                                             uint32_t* o0, uint32_t* o1) {
  uint32_t ks0 = k0, ks1 = k1, ks2 = k0 ^ k1 ^ 0x1BD11BDAu;
#define TF_ROT(v, d) (((v) << (d)) | ((v) >> (32 - (d))))
#define TF_ROUND(r) { x0 += x1; x1 = TF_ROT(x1, r); x1 ^= x0; }
  x0 += ks0; x1 += ks1;
  TF_ROUND(13) TF_ROUND(15) TF_ROUND(26) TF_ROUND(6)
  x0 += ks1; x1 += ks2 + 1u;
  TF_ROUND(17) TF_ROUND(29) TF_ROUND(16) TF_ROUND(24)
  x0 += ks2; x1 += ks0 + 2u;
  TF_ROUND(13) TF_ROUND(15) TF_ROUND(26) TF_ROUND(6)
  x0 += ks0; x1 += ks1 + 3u;
  TF_ROUND(17) TF_ROUND(29) TF_ROUND(16) TF_ROUND(24)
  x0 += ks1; x1 += ks2 + 4u;
  TF_ROUND(13) TF_ROUND(15) TF_ROUND(26) TF_ROUND(6)
  x0 += ks2; x1 += ks0 + 5u;
#undef TF_ROUND
#undef TF_ROT
  *o0 = x0; *o1 = x1;
}

// ---- XLA ErfInv32 (Giles polynomial) ----
__device__ __forceinline__ float erfinv_xla(float x) {
  float w = -log1pf(__fmul_rn(-x, x));
  float p;
  if (w < 5.0f) {
    w = __fadd_rn(w, -2.5f);
    p = 2.81022636e-08f;
    p = __fadd_rn(3.43273939e-07f, __fmul_rn(p, w));
    p = __fadd_rn(-3.5233877e-06f, __fmul_rn(p, w));
    p = __fadd_rn(-4.39150654e-06f, __fmul_rn(p, w));
    p = __fadd_rn(0.00021858087f, __fmul_rn(p, w));
    p = __fadd_rn(-0.00125372503f, __fmul_rn(p, w));
    p = __fadd_rn(-0.00417768164f, __fmul_rn(p, w));
    p = __fadd_rn(0.246640727f, __fmul_rn(p, w));
    p = __fadd_rn(1.50140941f, __fmul_rn(p, w));
  } else {
    w = __fadd_rn(sqrtf(w), -3.0f);
    p = -0.000200214257f;
    p = __fadd_rn(0.000100950558f, __fmul_rn(p, w));
    p = __fadd_rn(0.00134934322f, __fmul_rn(p, w));
    p = __fadd_rn(-0.00367342844f, __fmul_rn(p, w));
    p = __fadd_rn(0.00573950773f, __fmul_rn(p, w));
    p = __fadd_rn(-0.0076224613f, __fmul_rn(p, w));
    p = __fadd_rn(0.00943887047f, __fmul_rn(p, w));
    p = __fadd_rn(1.00167406f, __fmul_rn(p, w));
    p = __fadd_rn(2.83297682f, __fmul_rn(p, w));
  }
  return __fmul_rn(p, x);
}

// partitionable threefry noise (verified passing in round 6)
__device__ __forceinline__ float jax_normal_at(uint32_t i) {
  uint32_t o0, o1;
  threefry2x32(0u, 42u, 0u, i, &o0, &o1);
  uint32_t bits = o0 ^ o1;
  float f = __fadd_rn(__uint_as_float((bits >> 9) | 0x3f800000u), -1.0f);
  const float lo = -0.99999994f;
  float u = fmaxf(lo, __fadd_rn(__fmul_rn(f, 2.0f), lo));
  return __fmul_rn(1.4142135623730951f, erfinv_xla(u));
}

// ---------------- Router: 1 wave per token, fp64 (routing exactness) --------
__global__ __launch_bounds__(256) void router_kernel(
    const float* __restrict__ x, const float* __restrict__ Wr, const float* __restrict__ br,
    const float* __restrict__ Wn, const float* __restrict__ bn,
    int* __restrict__ counts, int* __restrict__ top_i, float* __restrict__ top_g) {
  int wave = threadIdx.x >> 6;
  int lane = threadIdx.x & 63;
  int t = blockIdx.x * 4 + wave;

  double accR[8], accN[8];
#pragma unroll
  for (int e = 0; e < 8; ++e) { accR[e] = 0.0; accN[e] = 0.0; }

  const float* xp = x + (size_t)t * DIM + lane * 8;
  float4 xa = *(const float4*)xp;
  float4 xb = *(const float4*)(xp + 4);
  float xv[8] = {xa.x, xa.y, xa.z, xa.w, xb.x, xb.y, xb.z, xb.w};

#pragma unroll
  for (int k = 0; k < 8; ++k) {
    int d = lane * 8 + k;
    float4 wra = *(const float4*)(Wr + (size_t)d * NEXP);
    float4 wrb = *(const float4*)(Wr + (size_t)d * NEXP + 4);
    float4 wna = *(const float4*)(Wn + (size_t)d * NEXP);
    float4 wnb = *(const float4*)(Wn + (size_t)d * NEXP + 4);
    float wr[8] = {wra.x, wra.y, wra.z, wra.w, wrb.x, wrb.y, wrb.z, wrb.w};
    float wn[8] = {wna.x, wna.y, wna.z, wna.w, wnb.x, wnb.y, wnb.z, wnb.w};
    double xk = (double)xv[k];
#pragma unroll
    for (int e = 0; e < 8; ++e) {
      accR[e] += xk * (double)wr[e];
      accN[e] += xk * (double)wn[e];
    }
  }
#pragma unroll
  for (int m = 1; m < 64; m <<= 1) {
#pragma unroll
    for (int e = 0; e < 8; ++e) {
      accR[e] += __shfl_xor(accR[e], m);
      accN[e] += __shfl_xor(accN[e], m);
    }
  }

  double noisy = -1.0e308;
  if (lane < 8) {
    int e = lane;
    double logit = accR[e] + (double)br[e];
    double nlin  = accN[e] + (double)bn[e];
    double noise = (double)jax_normal_at((uint32_t)t * 8u + (uint32_t)e);
    double sp = fmax(nlin, 0.0) + log1p(exp(-fabs(nlin)));
    noisy = logit + noise * sp;
  }
  double v[8];
#pragma unroll
  for (int e = 0; e < 8; ++e) v[e] = __shfl(noisy, e);

  if (lane == 0) {
    int i1 = 0; double v1 = v[0];
#pragma unroll
    for (int e = 1; e < 8; ++e) if (v[e] > v1) { v1 = v[e]; i1 = e; }
    int i2 = -1; double v2 = -1.0e308;
#pragma unroll
    for (int e = 0; e < 8; ++e) if (e != i1 && v[e] > v2) { v2 = v[e]; i2 = e; }
    double w2 = exp(v2 - v1);
    double s = 1.0 + w2;
    float g1 = (float)(1.0 / s), g2 = (float)(w2 / s);
    top_i[t * 2 + 0] = i1; top_g[t * 2 + 0] = g1;
    top_i[t * 2 + 1] = i2; top_g[t * 2 + 1] = g2;
    atomicAdd(&counts[i1], 1);
    atomicAdd(&counts[i2], 1);
  }
}

// offsets aligned to 32 so 32-token tiles never span experts
__global__ void scan_kernel(const int* __restrict__ counts, int* __restrict__ offsets) {
  if (threadIdx.x == 0 && blockIdx.x == 0) {
    int s = 0;
#pragma unroll
    for (int e = 0; e < NEXP; ++e) { offsets[e] = s; s += (counts[e] + 31) & ~31; }
  }
}

__global__ __launch_bounds__(256) void scatter_kernel(
    const int* __restrict__ top_i, const float* __restrict__ top_g,
    const int* __restrict__ offsets, int* __restrict__ fill,
    int* __restrict__ ltok, float* __restrict__ lgate) {
  int i = blockIdx.x * 256 + threadIdx.x;
  int e = top_i[i];
  float g = top_g[i];
  int pos = atomicAdd(&fill[e], 1);
  int dst = offsets[e] + pos;
  ltok[dst] = i >> 1;
  lgate[dst] = g;
}

// ---- pack W1 [e][d][h] fp32 -> B-frag slabs [e][h/16][d/8][16][8] bf16 ----
__global__ __launch_bounds__(256) void pack_w1(const float* __restrict__ W1,
                                               __bf16* __restrict__ W1p) {
  int e = blockIdx.x >> 7;          // 8
  int ht = blockIdx.x & 127;        // 128 h-tiles
  int t = threadIdx.x;
  int ko = t >> 2;                  // 64 d-octets
  int cbase = (t & 3) * 4;
  const float* src = W1 + (size_t)e * DIM * HID + ht * 16;
  __bf16* dst = W1p + ((size_t)(e * 128 + ht) * 64 + ko) * 128 + cbase * 8;
#pragma unroll
  for (int cc = 0; cc < 4; ++cc)
#pragma unroll
    for (int j = 0; j < 8; ++j)
      dst[cc * 8 + j] = (__bf16)src[(size_t)(ko * 8 + j) * HID + cbase + cc];
}

// ---- pack W2 [e][h][d] fp32 -> B-frag slabs [e][d/16][h/8][16][8] bf16 ----
__global__ __launch_bounds__(256) void pack_w2(const float* __restrict__ W2,
                                               __bf16* __restrict__ W2p) {
  int e = blockIdx.x >> 5;          // 8
  int dt = blockIdx.x & 31;         // 32 d-tiles
  int t = threadIdx.x;              // = h-octet 0..255
  const float* src = W2 + (size_t)e * HID * DIM + dt * 16;
  __bf16* dst = W2p + ((size_t)(e * 32 + dt) * 256 + t) * 128;
#pragma unroll
  for (int c = 0; c < 16; ++c)
#pragma unroll
    for (int j = 0; j < 8; ++j)
      dst[c * 8 + j] = (__bf16)src[(size_t)(t * 8 + j) * DIM + c];
}

// ---------------- Fused MFMA expert FFN: 32-token tiles ----------------
__global__ __launch_bounds__(256) void expert_mfma(
    const float* __restrict__ x,
    const __bf16* __restrict__ W1p, const float* __restrict__ b1,
    const __bf16* __restrict__ W2p, const float* __restrict__ b2,
    const int* __restrict__ counts, const int* __restrict__ offsets,
    const int* __restrict__ ltok, const float* __restrict__ lgate,
    float* __restrict__ out) {
  int e = blockIdx.x >> 10;
  int blk = blockIdx.x & 1023;
  int cnt = counts[e];
  int start = blk * 32;
  if (start >= cnt) return;
  int nrow = min(32, cnt - start);
  int base = offsets[e] + start;

  __shared__ __bf16 Xs[64][32][8];       // [k/8][m][j] A-frag layout, 32 KB
  __shared__ __bf16 Hs[2][16][32][8];    // dbuf, per-128-chunk, 16 KB
  __shared__ int   toks[32];
  __shared__ float gates[32];

  const int tid = threadIdx.x;
  const int lane = tid & 63;
  const int w = tid >> 6;         // wave 0..3
  const int lq = lane >> 4;       // quad 0..3
  const int lc = lane & 15;

  if (tid < 32) {
    int tk = 0; float g = 0.f;
    if (tid < nrow) { tk = ltok[base + tid]; g = lgate[base + tid]; }
    toks[tid] = tk; gates[tid] = g;
  }
  __syncthreads();

  // stage X tile: fp32 global -> bf16 LDS (A-frag k-octet-major layout)
  {
    int m = tid >> 3, seg = tid & 7;
    if (m < nrow) {
      const float* xp = x + (size_t)toks[m] * DIM + seg * 64;
#pragma unroll
      for (int s = 0; s < 8; ++s) {
        float4 f0 = *(const float4*)(xp + s * 8);
        float4 f1 = *(const float4*)(xp + s * 8 + 4);
        bf16x8 v;
        v[0] = (__bf16)f0.x; v[1] = (__bf16)f0.y; v[2] = (__bf16)f0.z; v[3] = (__bf16)f0.w;
        v[4] = (__bf16)f1.x; v[5] = (__bf16)f1.y; v[6] = (__bf16)f1.z; v[7] = (__bf16)f1.w;
        *(bf16x8*)&Xs[seg * 8 + s][m][0] = v;
      }
    } else {
      bf16x8 v;
#pragma unroll
      for (int j = 0; j < 8; ++j) v[j] = (__bf16)0.f;
#pragma unroll
      for (int s = 0; s < 8; ++s) *(bf16x8*)&Xs[seg * 8 + s][m][0] = v;
    }
  }
  __syncthreads();

  f32x4 acc2[2][8];
#pragma unroll
  for (int mt = 0; mt < 2; ++mt)
#pragma unroll
    for (int nt = 0; nt < 8; ++nt) acc2[mt][nt] = (f32x4){0.f, 0.f, 0.f, 0.f};

  const __bf16* w2s = W2p + (size_t)(e * 32 + w * 8) * 32768;

  for (int hc = 0; hc < 16; ++hc) {
    // ---- layer 1: H chunk cols [hc*128, +128); wave w owns local n [w*32,+32)
    f32x4 acc1[2][2];
#pragma unroll
    for (int mt = 0; mt < 2; ++mt)
#pragma unroll
      for (int ntl = 0; ntl < 2; ++ntl) acc1[mt][ntl] = (f32x4){0.f, 0.f, 0.f, 0.f};

    const __bf16* w1s0 = W1p + (size_t)(e * 128 + hc * 8 + w * 2) * 8192;
    const __bf16* w1s1 = w1s0 + 8192;
#pragma unroll
    for (int ks = 0; ks < 16; ++ks) {
      int ko = ks * 4 + lq;
      bf16x8 a0 = *(const bf16x8*)&Xs[ko][lc][0];
      bf16x8 a1 = *(const bf16x8*)&Xs[ko][16 + lc][0];
      int boff = (ko * 16 + lc) * 8;
      bf16x8 bv0 = *(const bf16x8*)(w1s0 + boff);
      bf16x8 bv1 = *(const bf16x8*)(w1s1 + boff);
      acc1[0][0] = mfma16(a0, bv0, acc1[0][0]);
      acc1[1][0] = mfma16(a1, bv0, acc1[1][0]);
      acc1[0][1] = mfma16(a0, bv1, acc1[0][1]);
      acc1[1][1] = mfma16(a1, bv1, acc1[1][1]);
    }
    // bias + relu + bf16, write to Hs in A-frag layout
    int buf = hc & 1;
    float bias0 = b1[e * HID + hc * 128 + w * 32 + lc];
    float bias1 = b1[e * HID + hc * 128 + w * 32 + 16 + lc];
    int ko2w = w * 4 + (lc >> 3);
#pragma unroll
    for (int mt = 0; mt < 2; ++mt)
#pragma unroll
      for (int ntl = 0; ntl < 2; ++ntl) {
        float bias = ntl ? bias1 : bias0;
#pragma unroll
        for (int r = 0; r < 4; ++r) {
          float v = fmaxf(acc1[mt][ntl][r] + bias, 0.f);
          Hs[buf][ko2w + ntl * 2][mt * 16 + lq * 4 + r][lane & 7] = (__bf16)v;
        }
      }
    __syncthreads();

    // ---- layer 2 partial: Y[:, w*128..+128) += H_chunk @ W2[chunk rows]
#pragma unroll
    for (int ks2 = 0; ks2 < 4; ++ks2) {
      bf16x8 h0 = *(const bf16x8*)&Hs[buf][ks2 * 4 + lq][lc][0];
      bf16x8 h1 = *(const bf16x8*)&Hs[buf][ks2 * 4 + lq][16 + lc][0];
      int boff = ((hc * 16 + ks2 * 4 + lq) * 16 + lc) * 8;
#pragma unroll
      for (int nt = 0; nt < 8; ++nt) {
        bf16x8 bb = *(const bf16x8*)(w2s + nt * 32768 + boff);
        acc2[0][nt] = mfma16(h0, bb, acc2[0][nt]);
        acc2[1][nt] = mfma16(h1, bb, acc2[1][nt]);
      }
    }
  }

  // epilogue: gate-weighted atomic accumulate into fp32 out
#pragma unroll
  for (int nt = 0; nt < 8; ++nt) {
    int d = w * 128 + nt * 16 + lc;
    float b2v = b2[e * DIM + d];
#pragma unroll
    for (int mt = 0; mt < 2; ++mt)
#pragma unroll
      for (int r = 0; r < 4; ++r) {
        int m = mt * 16 + lq * 4 + r;
        atomicAdd(out + (size_t)toks[m] * DIM + d, gates[m] * (acc2[mt][nt][r] + b2v));
      }
  }
}

extern "C" void kernel_launch(void* const* d_in, const int* in_sizes, int n_in,
                              void* d_out, int out_size, void* d_ws, size_t ws_size,
                              hipStream_t stream) {
  const float* x  = (const float*)d_in[0];
  const float* Wr = (const float*)d_in[1];
  const float* br = (const float*)d_in[2];
  const float* Wn = (const float*)d_in[3];
  const float* bn = (const float*)d_in[4];
  const float* W1 = (const float*)d_in[5];
  const float* b1 = (const float*)d_in[6];
  const float* W2 = (const float*)d_in[7];
  const float* b2 = (const float*)d_in[8];
  float* out = (float*)d_out;

  uint8_t* wsb = (uint8_t*)d_ws;
  int* counts   = (int*)(wsb);
  int* offsets  = (int*)(wsb + 32);
  int* fill     = (int*)(wsb + 64);
  int* top_i    = (int*)(wsb + 128);
  float* top_g  = (float*)(wsb + 131200);
  int* ltok     = (int*)(wsb + 262272);
  float* lgate  = (float*)(wsb + 394368);
  __bf16* W1p   = (__bf16*)(wsb + 532480);
  __bf16* W2p   = (__bf16*)(wsb + 532480 + 16777216);
  // total ws usage: 532480 + 2*16777216 = 34,087,680 bytes (~34.1 MB)

  hipMemsetAsync(out, 0, (size_t)out_size * sizeof(float), stream);
  hipMemsetAsync(wsb, 0, 128, stream);

  pack_w1<<<NEXP * 128, 256, 0, stream>>>(W1, W1p);
  pack_w2<<<NEXP * 32, 256, 0, stream>>>(W2, W2p);
  router_kernel<<<T_TOKENS / 4, 256, 0, stream>>>(x, Wr, br, Wn, bn, counts, top_i, top_g);
  scan_kernel<<<1, 64, 0, stream>>>(counts, offsets);
  scatter_kernel<<<(2 * T_TOKENS) / 256, 256, 0, stream>>>(top_i, top_g, offsets, fill, ltok, lgate);
  expert_mfma<<<NEXP * 1024, 256, 0, stream>>>(x, W1p, b1, W2p, b2, counts, offsets, ltok, lgate, out);
}

// Round 8
// 1136.739 us; speedup vs baseline: 3.4651x; 1.0503x over previous
//
#include <hip/hip_runtime.h>
#include <hip/hip_bf16.h>
#include <stdint.h>
#include <math.h>

#define T_TOKENS 16384
#define DIM      512
#define NEXP     8
#define HID      2048

typedef __attribute__((ext_vector_type(8))) __bf16 bf16x8;
typedef __attribute__((ext_vector_type(4))) float  f32x4;

__device__ __forceinline__ f32x4 mfma16(bf16x8 a, bf16x8 b, f32x4 c) {
  return __builtin_amdgcn_mfma_f32_16x16x32_bf16(a, b, c, 0, 0, 0);
}

// ---- JAX threefry2x32, key = (0, 42) ----
__device__ __forceinline__ void threefry2x32(uint32_t k0, uint32_t k1,
                                             uint32_t x0, uint32_t x1,
                                             uint32_t* o0, uint32_t* o1) {
  uint32_t ks0 = k0, ks1 = k1, ks2 = k0 ^ k1 ^ 0x1BD11BDAu;
#define TF_ROT(v, d) (((v) << (d)) | ((v) >> (32 - (d))))
#define TF_ROUND(r) { x0 += x1; x1 = TF_ROT(x1, r); x1 ^= x0; }
  x0 += ks0; x1 += ks1;
  TF_ROUND(13) TF_ROUND(15) TF_ROUND(26) TF_ROUND(6)
  x0 += ks1; x1 += ks2 + 1u;
  TF_ROUND(17) TF_ROUND(29) TF_ROUND(16) TF_ROUND(24)
  x0 += ks2; x1 += ks0 + 2u;
  TF_ROUND(13) TF_ROUND(15) TF_ROUND(26) TF_ROUND(6)
  x0 += ks0; x1 += ks1 + 3u;
  TF_ROUND(17) TF_ROUND(29) TF_ROUND(16) TF_ROUND(24)
  x0 += ks1; x1 += ks2 + 4u;
  TF_ROUND(13) TF_ROUND(15) TF_ROUND(26) TF_ROUND(6)
  x0 += ks2; x1 += ks0 + 5u;
#undef TF_ROUND
#undef TF_ROT
  *o0 = x0; *o1 = x1;
}

// ---- XLA ErfInv32 (Giles polynomial) ----
__device__ __forceinline__ float erfinv_xla(float x) {
  float w = -log1pf(__fmul_rn(-x, x));
  float p;
  if (w < 5.0f) {
    w = __fadd_rn(w, -2.5f);
    p = 2.81022636e-08f;
    p = __fadd_rn(3.43273939e-07f, __fmul_rn(p, w));
    p = __fadd_rn(-3.5233877e-06f, __fmul_rn(p, w));
    p = __fadd_rn(-4.39150654e-06f, __fmul_rn(p, w));
    p = __fadd_rn(0.00021858087f, __fmul_rn(p, w));
    p = __fadd_rn(-0.00125372503f, __fmul_rn(p, w));
    p = __fadd_rn(-0.00417768164f, __fmul_rn(p, w));
    p = __fadd_rn(0.246640727f, __fmul_rn(p, w));
    p = __fadd_rn(1.50140941f, __fmul_rn(p, w));
  } else {
    w = __fadd_rn(sqrtf(w), -3.0f);
    p = -0.000200214257f;
    p = __fadd_rn(0.000100950558f, __fmul_rn(p, w));
    p = __fadd_rn(0.00134934322f, __fmul_rn(p, w));
    p = __fadd_rn(-0.00367342844f, __fmul_rn(p, w));
    p = __fadd_rn(0.00573950773f, __fmul_rn(p, w));
    p = __fadd_rn(-0.0076224613f, __fmul_rn(p, w));
    p = __fadd_rn(0.00943887047f, __fmul_rn(p, w));
    p = __fadd_rn(1.00167406f, __fmul_rn(p, w));
    p = __fadd_rn(2.83297682f, __fmul_rn(p, w));
  }
  return __fmul_rn(p, x);
}

__device__ __forceinline__ float jax_normal_at(uint32_t i) {
  uint32_t o0, o1;
  threefry2x32(0u, 42u, 0u, i, &o0, &o1);
  uint32_t bits = o0 ^ o1;
  float f = __fadd_rn(__uint_as_float((bits >> 9) | 0x3f800000u), -1.0f);
  const float lo = -0.99999994f;
  float u = fmaxf(lo, __fadd_rn(__fmul_rn(f, 2.0f), lo));
  return __fmul_rn(1.4142135623730951f, erfinv_xla(u));
}

// ---------------- Router: 1 wave per token, fp64 ----------------
__global__ __launch_bounds__(256) void router_kernel(
    const float* __restrict__ x, const float* __restrict__ Wr, const float* __restrict__ br,
    const float* __restrict__ Wn, const float* __restrict__ bn,
    int* __restrict__ counts, int* __restrict__ top_i, float* __restrict__ top_g) {
  int wave = threadIdx.x >> 6;
  int lane = threadIdx.x & 63;
  int t = blockIdx.x * 4 + wave;

  double accR[8], accN[8];
#pragma unroll
  for (int e = 0; e < 8; ++e) { accR[e] = 0.0; accN[e] = 0.0; }

  const float* xp = x + (size_t)t * DIM + lane * 8;
  float4 xa = *(const float4*)xp;
  float4 xb = *(const float4*)(xp + 4);
  float xv[8] = {xa.x, xa.y, xa.z, xa.w, xb.x, xb.y, xb.z, xb.w};

#pragma unroll
  for (int k = 0; k < 8; ++k) {
    int d = lane * 8 + k;
    float4 wra = *(const float4*)(Wr + (size_t)d * NEXP);
    float4 wrb = *(const float4*)(Wr + (size_t)d * NEXP + 4);
    float4 wna = *(const float4*)(Wn + (size_t)d * NEXP);
    float4 wnb = *(const float4*)(Wn + (size_t)d * NEXP + 4);
    float wr[8] = {wra.x, wra.y, wra.z, wra.w, wrb.x, wrb.y, wrb.z, wrb.w};
    float wn[8] = {wna.x, wna.y, wna.z, wna.w, wnb.x, wnb.y, wnb.z, wnb.w};
    double xk = (double)xv[k];
#pragma unroll
    for (int e = 0; e < 8; ++e) {
      accR[e] += xk * (double)wr[e];
      accN[e] += xk * (double)wn[e];
    }
  }
#pragma unroll
  for (int m = 1; m < 64; m <<= 1) {
#pragma unroll
    for (int e = 0; e < 8; ++e) {
      accR[e] += __shfl_xor(accR[e], m);
      accN[e] += __shfl_xor(accN[e], m);
    }
  }

  double noisy = -1.0e308;
  if (lane < 8) {
    int e = lane;
    double logit = accR[e] + (double)br[e];
    double nlin  = accN[e] + (double)bn[e];
    double noise = (double)jax_normal_at((uint32_t)t * 8u + (uint32_t)e);
    double sp = fmax(nlin, 0.0) + log1p(exp(-fabs(nlin)));
    noisy = logit + noise * sp;
  }
  double v[8];
#pragma unroll
  for (int e = 0; e < 8; ++e) v[e] = __shfl(noisy, e);

  if (lane == 0) {
    int i1 = 0; double v1 = v[0];
#pragma unroll
    for (int e = 1; e < 8; ++e) if (v[e] > v1) { v1 = v[e]; i1 = e; }
    int i2 = -1; double v2 = -1.0e308;
#pragma unroll
    for (int e = 0; e < 8; ++e) if (e != i1 && v[e] > v2) { v2 = v[e]; i2 = e; }
    double w2 = exp(v2 - v1);
    double s = 1.0 + w2;
    float g1 = (float)(1.0 / s), g2 = (float)(w2 / s);
    top_i[t * 2 + 0] = i1; top_g[t * 2 + 0] = g1;
    top_i[t * 2 + 1] = i2; top_g[t * 2 + 1] = g2;
    atomicAdd(&counts[i1], 1);
    atomicAdd(&counts[i2], 1);
  }
}

// offsets aligned to 32 so 32-token tiles never span experts
__global__ void scan_kernel(const int* __restrict__ counts, int* __restrict__ offsets) {
  if (threadIdx.x == 0 && blockIdx.x == 0) {
    int s = 0;
#pragma unroll
    for (int e = 0; e < NEXP; ++e) { offsets[e] = s; s += (counts[e] + 31) & ~31; }
  }
}

__global__ __launch_bounds__(256) void scatter_kernel(
    const int* __restrict__ top_i, const float* __restrict__ top_g,
    const int* __restrict__ offsets, int* __restrict__ fill,
    int* __restrict__ ltok, float* __restrict__ lgate) {
  int i = blockIdx.x * 256 + threadIdx.x;
  int e = top_i[i];
  float g = top_g[i];
  int pos = atomicAdd(&fill[e], 1);
  int dst = offsets[e] + pos;
  ltok[dst] = i >> 1;
  lgate[dst] = g;
}

// ---- generic transpose-pack: src [e][R][C] fp32 -> [e][C/16][R/8][16][8] bf16
// dst[e][nt][ko][lc][j] = src[e][ko*8+j][nt*16+lc]; coalesced via LDS transpose.
__global__ __launch_bounds__(256) void pack_bfrag(const float* __restrict__ src,
                                                  __bf16* __restrict__ dst,
                                                  int R, int C) {
  int nct = C >> 6;
  int tilesPerE = (R >> 6) * nct;
  int e = blockIdx.x / tilesPerE;
  int rem = blockIdx.x % tilesPerE;
  int rt = rem / nct, ct = rem % nct;

  __shared__ float Ls[64][68];   // pad 68 (16B-aligned rows, bank-skewed)

  const float* s = src + (size_t)e * R * C + (size_t)(rt * 64) * C + ct * 64;
  int row = threadIdx.x >> 4;
  int col = (threadIdx.x & 15) * 4;
#pragma unroll
  for (int it = 0; it < 4; ++it) {
    float4 v = *(const float4*)(s + (size_t)(it * 16 + row) * C + col);
    *(float4*)&Ls[it * 16 + row][col] = v;
  }
  __syncthreads();

  int rOver8 = R >> 3;
#pragma unroll
  for (int q = 0; q < 2; ++q) {
    int f = threadIdx.x + q * 256;       // (htl*8 + kol)*16 + lc
    int lc = f & 15;
    int kol = (f >> 4) & 7;
    int htl = f >> 7;
    int hl = htl * 16 + lc;
    bf16x8 v;
#pragma unroll
    for (int j = 0; j < 8; ++j) v[j] = (__bf16)Ls[kol * 8 + j][hl];
    size_t idx = ((size_t)(e * (C >> 4) + ct * 4 + htl) * rOver8 + rt * 8 + kol) * 128 + lc * 8;
    *(bf16x8*)(dst + idx) = v;
  }
}

// ---------------- Fused MFMA expert FFN: 32-token tiles, XCD-pinned --------
__global__ __launch_bounds__(256) void expert_mfma(
    const float* __restrict__ x,
    const __bf16* __restrict__ W1p, const float* __restrict__ b1,
    const __bf16* __restrict__ W2p, const float* __restrict__ b2,
    const int* __restrict__ counts, const int* __restrict__ offsets,
    const int* __restrict__ ltok, const float* __restrict__ lgate,
    float* __restrict__ out) {
  // XCD pinning: consecutive blocks round-robin across XCDs; e = blk&7 keeps
  // each expert's 4MB weight set resident in one XCD's L2.
  const int e = blockIdx.x & 7;
  const int tslot = blockIdx.x >> 3;      // 0..255
  const int cnt = counts[e];

  __shared__ __bf16 Xs[64][32][8];       // [k/8][m][j] A-frag layout, 32 KB
  __shared__ __bf16 Hs[2][16][32][8];    // dbuf per-128-chunk, 16 KB
  __shared__ int   toks[32];
  __shared__ float gates[32];

  const int tid = threadIdx.x;
  const int lane = tid & 63;
  const int w = tid >> 6;
  const int lq = lane >> 4;
  const int lc = lane & 15;

  const __bf16* w2s = W2p + (size_t)(e * 32 + w * 8) * 32768;

  for (int tile = tslot; tile * 32 < cnt; tile += 256) {
    int start = tile * 32;
    int nrow = min(32, cnt - start);
    int base = offsets[e] + start;

    __syncthreads();   // prev tile's epilogue reads of toks/gates done
    if (tid < 32) {
      int tk = 0; float g = 0.f;
      if (tid < nrow) { tk = ltok[base + tid]; g = lgate[base + tid]; }
      toks[tid] = tk; gates[tid] = g;
    }
    __syncthreads();

    // stage X tile: fp32 global -> bf16 LDS (A-frag k-octet-major)
    {
      int m = tid >> 3, seg = tid & 7;
      if (m < nrow) {
        const float* xp = x + (size_t)toks[m] * DIM + seg * 64;
#pragma unroll
        for (int s = 0; s < 8; ++s) {
          float4 f0 = *(const float4*)(xp + s * 8);
          float4 f1 = *(const float4*)(xp + s * 8 + 4);
          bf16x8 v;
          v[0] = (__bf16)f0.x; v[1] = (__bf16)f0.y; v[2] = (__bf16)f0.z; v[3] = (__bf16)f0.w;
          v[4] = (__bf16)f1.x; v[5] = (__bf16)f1.y; v[6] = (__bf16)f1.z; v[7] = (__bf16)f1.w;
          *(bf16x8*)&Xs[seg * 8 + s][m][0] = v;
        }
      } else {
        bf16x8 v;
#pragma unroll
        for (int j = 0; j < 8; ++j) v[j] = (__bf16)0.f;
#pragma unroll
        for (int s = 0; s < 8; ++s) *(bf16x8*)&Xs[seg * 8 + s][m][0] = v;
      }
    }
    __syncthreads();

    f32x4 acc2[2][8];
#pragma unroll
    for (int mt = 0; mt < 2; ++mt)
#pragma unroll
      for (int nt = 0; nt < 8; ++nt) acc2[mt][nt] = (f32x4){0.f, 0.f, 0.f, 0.f};

    for (int hc = 0; hc < 16; ++hc) {
      f32x4 acc1[2][2];
#pragma unroll
      for (int mt = 0; mt < 2; ++mt)
#pragma unroll
        for (int ntl = 0; ntl < 2; ++ntl) acc1[mt][ntl] = (f32x4){0.f, 0.f, 0.f, 0.f};

      const __bf16* w1s0 = W1p + (size_t)(e * 128 + hc * 8 + w * 2) * 8192;
      const __bf16* w1s1 = w1s0 + 8192;
#pragma unroll
      for (int ks = 0; ks < 16; ++ks) {
        int ko = ks * 4 + lq;
        bf16x8 a0 = *(const bf16x8*)&Xs[ko][lc][0];
        bf16x8 a1 = *(const bf16x8*)&Xs[ko][16 + lc][0];
        int boff = (ko * 16 + lc) * 8;
        bf16x8 bv0 = *(const bf16x8*)(w1s0 + boff);
        bf16x8 bv1 = *(const bf16x8*)(w1s1 + boff);
        acc1[0][0] = mfma16(a0, bv0, acc1[0][0]);
        acc1[1][0] = mfma16(a1, bv0, acc1[1][0]);
        acc1[0][1] = mfma16(a0, bv1, acc1[0][1]);
        acc1[1][1] = mfma16(a1, bv1, acc1[1][1]);
      }
      int buf = hc & 1;
      float bias0 = b1[e * HID + hc * 128 + w * 32 + lc];
      float bias1 = b1[e * HID + hc * 128 + w * 32 + 16 + lc];
      int ko2w = w * 4 + (lc >> 3);
#pragma unroll
      for (int mt = 0; mt < 2; ++mt)
#pragma unroll
        for (int ntl = 0; ntl < 2; ++ntl) {
          float bias = ntl ? bias1 : bias0;
#pragma unroll
          for (int r = 0; r < 4; ++r) {
            float v = fmaxf(acc1[mt][ntl][r] + bias, 0.f);
            Hs[buf][ko2w + ntl * 2][mt * 16 + lq * 4 + r][lane & 7] = (__bf16)v;
          }
        }
      __syncthreads();

#pragma unroll
      for (int ks2 = 0; ks2 < 4; ++ks2) {
        bf16x8 h0 = *(const bf16x8*)&Hs[buf][ks2 * 4 + lq][lc][0];
        bf16x8 h1 = *(const bf16x8*)&Hs[buf][ks2 * 4 + lq][16 + lc][0];
        int boff = ((hc * 16 + ks2 * 4 + lq) * 16 + lc) * 8;
#pragma unroll
        for (int nt = 0; nt < 8; ++nt) {
          bf16x8 bb = *(const bf16x8*)(w2s + nt * 32768 + boff);
          acc2[0][nt] = mfma16(h0, bb, acc2[0][nt]);
          acc2[1][nt] = mfma16(h1, bb, acc2[1][nt]);
        }
      }
    }

    // epilogue: gate-weighted atomic accumulate into fp32 out
#pragma unroll
    for (int nt = 0; nt < 8; ++nt) {
      int d = w * 128 + nt * 16 + lc;
      float b2v = b2[e * DIM + d];
#pragma unroll
      for (int mt = 0; mt < 2; ++mt)
#pragma unroll
        for (int r = 0; r < 4; ++r) {
          int m = mt * 16 + lq * 4 + r;
          atomicAdd(out + (size_t)toks[m] * DIM + d, gates[m] * (acc2[mt][nt][r] + b2v));
        }
    }
  }
}

extern "C" void kernel_launch(void* const* d_in, const int* in_sizes, int n_in,
                              void* d_out, int out_size, void* d_ws, size_t ws_size,
                              hipStream_t stream) {
  const float* x  = (const float*)d_in[0];
  const float* Wr = (const float*)d_in[1];
  const float* br = (const float*)d_in[2];
  const float* Wn = (const float*)d_in[3];
  const float* bn = (const float*)d_in[4];
  const float* W1 = (const float*)d_in[5];
  const float* b1 = (const float*)d_in[6];
  const float* W2 = (const float*)d_in[7];
  const float* b2 = (const float*)d_in[8];
  float* out = (float*)d_out;

  uint8_t* wsb = (uint8_t*)d_ws;
  int* counts   = (int*)(wsb);
  int* offsets  = (int*)(wsb + 32);
  int* fill     = (int*)(wsb + 64);
  int* top_i    = (int*)(wsb + 128);
  float* top_g  = (float*)(wsb + 131200);
  int* ltok     = (int*)(wsb + 262272);
  float* lgate  = (float*)(wsb + 394368);
  __bf16* W1p   = (__bf16*)(wsb + 532480);
  __bf16* W2p   = (__bf16*)(wsb + 532480 + 16777216);
  // total ws usage: 532480 + 2*16777216 = 34,087,680 bytes (~34.1 MB)

  hipMemsetAsync(out, 0, (size_t)out_size * sizeof(float), stream);
  hipMemsetAsync(wsb, 0, 128, stream);

  pack_bfrag<<<2048, 256, 0, stream>>>(W1, W1p, DIM, HID);   // 8*(512/64)*(2048/64)
  pack_bfrag<<<2048, 256, 0, stream>>>(W2, W2p, HID, DIM);   // 8*(2048/64)*(512/64)
  router_kernel<<<T_TOKENS / 4, 256, 0, stream>>>(x, Wr, br, Wn, bn, counts, top_i, top_g);
  scan_kernel<<<1, 64, 0, stream>>>(counts, offsets);
  scatter_kernel<<<(2 * T_TOKENS) / 256, 256, 0, stream>>>(top_i, top_g, offsets, fill, ltok, lgate);
  expert_mfma<<<2048, 256, 0, stream>>>(x, W1p, b1, W2p, b2, counts, offsets, ltok, lgate, out);
}